// Round 3
// baseline (39997.363 us; speedup 1.0000x reference)
//
#include <hip/hip_runtime.h>
#include <math.h>

namespace {
constexpr int kB = 64;
constexpr int kT = 1024;
constexpr int kH = 512;
constexpr int kL = 3;
constexpr int kG = 2048;  // 4*H, gate order i,f,g,o
constexpr int RB = 8;     // recurrence blocks (weights-stationary)
constexpr int JPB = kH / RB;  // 64 hidden units per block

typedef _Float16 half8 __attribute__((ext_vector_type(8)));
typedef float floatx4 __attribute__((ext_vector_type(4)));
typedef unsigned long long ull;
typedef unsigned long long ull2 __attribute__((ext_vector_type(2)));

// ---------------- device-coherent access helpers ----------------
// h stores: per-access device scope (proven in rounds 0-1).
__device__ __forceinline__ void st_h_dev(_Float16* p, unsigned v) {
  asm volatile("global_store_short %0, %1, off sc0 sc1" : : "v"(p), "v"(v));
}
// A-fragment load: 2x8B relaxed agent atomic loads. Compiler-tracked vmcnt
// (unlike inline-asm loads) + proven-coherent lowering (round-1 poll used
// exactly this primitive to observe remote sc1 stores).
__device__ __forceinline__ half8 ld_af(const _Float16* p) {
  const ull* q = reinterpret_cast<const ull*>(p);
  ull2 v;
  v.x = __hip_atomic_load(q, __ATOMIC_RELAXED, __HIP_MEMORY_SCOPE_AGENT);
  v.y = __hip_atomic_load(q + 1, __ATOMIC_RELAXED, __HIP_MEMORY_SCOPE_AGENT);
  return __builtin_bit_cast(half8, v);
}

// ---------------- prep / init kernels ----------------
__global__ void prep_bias_kernel(const float* __restrict__ bih,
                                 const float* __restrict__ bhh,
                                 float* __restrict__ bias) {
  int i = blockIdx.x * blockDim.x + threadIdx.x;
  if (i < kG) bias[i] = bih[i] + bhh[i];
}

__global__ void prep_wf16_kernel(const float* __restrict__ whh,
                                 _Float16* __restrict__ wf) {
  int i = blockIdx.x * blockDim.x + threadIdx.x;  // kG*kH total
  wf[i] = (_Float16)whh[i];
}

__global__ void zero_f32_kernel(float* __restrict__ p, int n) {
  int i = blockIdx.x * blockDim.x + threadIdx.x;
  if (i < n) p[i] = 0.f;
}

// ---------------- input projection (unchanged fp32 GEMM) ----------------
constexpr int BM = 64, BN = 64, BK = 16;
__global__ __launch_bounds__(256) void proj_kernel(
    const float* __restrict__ A, const float* __restrict__ W,
    const float* __restrict__ bias, float* __restrict__ xg, int t0, int Tc) {
  __shared__ __align__(16) float As[BK][BM + 4];
  __shared__ __align__(16) float Bs[BK][BN + 4];
  const int tid = threadIdx.x;
  const int n0 = blockIdx.x * BN;
  const int r0 = blockIdx.y * BM;  // row = b*Tc + tl
  const int lr = tid >> 2;
  const int lk = (tid & 3) << 2;
  const int r = r0 + lr;
  const int b = r / Tc;
  const int tl = r - b * Tc;
  const float* arow = A + (size_t)(b * kT + t0 + tl) * kH;
  const float* wrow = W + (size_t)(n0 + lr) * kH;
  const int tx = tid & 15, ty = tid >> 4;
  float acc[4][4];
#pragma unroll
  for (int i = 0; i < 4; ++i)
#pragma unroll
    for (int j = 0; j < 4; ++j) acc[i][j] = 0.f;

  for (int k0 = 0; k0 < kH; k0 += BK) {
    float4 av = *reinterpret_cast<const float4*>(arow + k0 + lk);
    float4 bv = *reinterpret_cast<const float4*>(wrow + k0 + lk);
    As[lk + 0][lr] = av.x; As[lk + 1][lr] = av.y;
    As[lk + 2][lr] = av.z; As[lk + 3][lr] = av.w;
    Bs[lk + 0][lr] = bv.x; Bs[lk + 1][lr] = bv.y;
    Bs[lk + 2][lr] = bv.z; Bs[lk + 3][lr] = bv.w;
    __syncthreads();
#pragma unroll
    for (int kk = 0; kk < BK; ++kk) {
      float4 a4 = *reinterpret_cast<const float4*>(&As[kk][ty << 2]);
      float4 b4 = *reinterpret_cast<const float4*>(&Bs[kk][tx << 2]);
      float a[4] = {a4.x, a4.y, a4.z, a4.w};
      float bb[4] = {b4.x, b4.y, b4.z, b4.w};
#pragma unroll
      for (int i = 0; i < 4; ++i)
#pragma unroll
        for (int j = 0; j < 4; ++j) acc[i][j] += a[i] * bb[j];
    }
    __syncthreads();
  }
#pragma unroll
  for (int i = 0; i < 4; ++i) {
    int row = r0 + (ty << 2) + i;
    int col = n0 + (tx << 2);
    float4 o;
    o.x = acc[i][0] + bias[col + 0];
    o.y = acc[i][1] + bias[col + 1];
    o.z = acc[i][2] + bias[col + 2];
    o.w = acc[i][3] + bias[col + 3];
    *reinterpret_cast<float4*>(xg + (size_t)row * kG + col) = o;
  }
}

__device__ __forceinline__ float sigf(float x) {
  return 1.f / (1.f + __expf(-x));
}
__device__ __forceinline__ float tanh_fast(float x) {
  float e = __expf(2.f * x);
  return (e - 1.f) / (e + 1.f);
}

// ---------------- persistent weights-stationary recurrence ----------------
// 8 blocks x 256 threads. Block owns hidden slice [bid*64, bid*64+64) across
// all 4 gates. W held in regs as MFMA B-fragments. H ping-pongs through the
// device coherence point; A-fragments are loaded DIRECTLY from hg (identity
// layout — no LDS staging, no stage barrier). Barrier: per-block flag lines
// (64B apart) bumped with fetch_add, 8 parallel poll lanes.
__global__ __launch_bounds__(256, 1) void recur_mfma(
    const _Float16* __restrict__ wf, const float* __restrict__ xg,
    _Float16* __restrict__ hg,  // 2 * 32768 halves, frag-linear ping-pong
    float* __restrict__ out, float* __restrict__ c_state,
    unsigned* __restrict__ flags,  // 8 flags, 64B apart, zeroed per dispatch
    int t0, int Tc) {
  const int tid = threadIdx.x;
  const int w = tid >> 6;       // wave 0..3
  const int lane = tid & 63;
  const int l15 = lane & 15;    // MFMA col / m
  const int q = lane >> 4;      // MFMA quad
  const int bid = blockIdx.x;
  const int jl = w * 16 + l15;       // block-local hidden 0..63
  const int jg = bid * JPB + jl;     // global hidden 0..511

  // --- preload W B-fragments into registers (persistent) ---
  half8 wfrag[4][16];
#pragma unroll
  for (int g = 0; g < 4; ++g) {
    const _Float16* wr = wf + (size_t)(g * kH + jg) * kH;
#pragma unroll
    for (int ks = 0; ks < 16; ++ks)
      wfrag[g][ks] = *reinterpret_cast<const half8*>(wr + ks * 32 + q * 8);
  }
  // --- preload cell state ---
  float c[4][4];
#pragma unroll
  for (int mt = 0; mt < 4; ++mt)
#pragma unroll
    for (int rg = 0; rg < 4; ++rg) {
      int b = mt * 16 + q * 4 + rg;
      c[mt][rg] = c_state[b * kH + jg];
    }

  const int ksj = bid * 2 + (jl >> 5);  // k-region of this thread's h writes
  const int quadj = (jl >> 3) & 3;
  const int jj = jl & 7;

  for (int t = 0; t < Tc; ++t) {
    const _Float16* __restrict__ hin = hg + (size_t)(t & 1) * 32768;
    _Float16* __restrict__ hout = hg + (size_t)((t & 1) ^ 1) * 32768;

    // xg prefetch — DRAM latency hides under the MFMA phase.
    float xv[4][4][4];
#pragma unroll
    for (int mt = 0; mt < 4; ++mt)
#pragma unroll
      for (int g = 0; g < 4; ++g)
#pragma unroll
        for (int rg = 0; rg < 4; ++rg) {
          int b = mt * 16 + q * 4 + rg;
          xv[mt][g][rg] = xg[(size_t)(b * Tc + t) * kG + g * kH + jg];
        }

    floatx4 zero4 = {0.f, 0.f, 0.f, 0.f};
    floatx4 acc[4][4];
#pragma unroll
    for (int mt = 0; mt < 4; ++mt)
#pragma unroll
      for (int g = 0; g < 4; ++g) acc[mt][g] = zero4;

    // MFMA loop: A-fragments straight from hg (frag-linear identity layout),
    // compiler-tracked vmcnt pipelines the loads under the MFMAs.
#pragma unroll
    for (int ks = 0; ks < 16; ++ks) {
      half8 af[4];
#pragma unroll
      for (int mt = 0; mt < 4; ++mt)
        af[mt] = ld_af(hin + ((mt * 16 + ks) * 64 + lane) * 8);
#pragma unroll
      for (int mt = 0; mt < 4; ++mt)
#pragma unroll
        for (int g = 0; g < 4; ++g)
          acc[mt][g] = __builtin_amdgcn_mfma_f32_16x16x32_f16(
              af[mt], wfrag[g][ks], acc[mt][g], 0, 0, 0);
    }

    // elementwise LSTM update — all 4 gates of (b, jg) live in this lane.
    // h -> device-coherent frag-linear scatter (round-1-proven layout);
    // f32 h kept in hreg for the out store after the signal.
    float hreg[4][4];
#pragma unroll
    for (int mt = 0; mt < 4; ++mt)
#pragma unroll
      for (int rg = 0; rg < 4; ++rg) {
        int b = mt * 16 + q * 4 + rg;
        float gi = acc[mt][0][rg] + xv[mt][0][rg];
        float gf = acc[mt][1][rg] + xv[mt][1][rg];
        float gg = acc[mt][2][rg] + xv[mt][2][rg];
        float go = acc[mt][3][rg] + xv[mt][3][rg];
        float ig = sigf(gi), fg = sigf(gf), zg = tanh_fast(gg), og = sigf(go);
        float cn = fg * c[mt][rg] + ig * zg;
        c[mt][rg] = cn;
        float h = og * tanh_fast(cn);
        hreg[mt][rg] = h;
        _Float16 hf = (_Float16)h;
        st_h_dev(hout + ((((b >> 4) * 16 + ksj) * 64 + quadj * 16 +
                          (b & 15)) * 8 + jj),
                 (unsigned)__builtin_bit_cast(unsigned short, hf));
      }

    // drain h stores (ack = at coherence point), then signal this block's
    // flag line; out stores overlap the poll wait.
    asm volatile("s_waitcnt vmcnt(0)" ::: "memory");
    __syncthreads();
    if (tid == 0)
      __hip_atomic_fetch_add(flags + bid * 16, 1u, __ATOMIC_RELAXED,
                             __HIP_MEMORY_SCOPE_AGENT);
#pragma unroll
    for (int mt = 0; mt < 4; ++mt)
#pragma unroll
      for (int rg = 0; rg < 4; ++rg) {
        int b = mt * 16 + q * 4 + rg;
        out[(size_t)b * (kT * kH) + (size_t)(t0 + t) * kH + jg] =
            hreg[mt][rg];
      }
    unsigned tgt = (unsigned)(t + 1);
    if (tid < 8) {
      while (__hip_atomic_load(flags + tid * 16, __ATOMIC_RELAXED,
                               __HIP_MEMORY_SCOPE_AGENT) < tgt)
        __builtin_amdgcn_s_sleep(1);
    }
    __syncthreads();
  }

#pragma unroll
  for (int mt = 0; mt < 4; ++mt)
#pragma unroll
    for (int rg = 0; rg < 4; ++rg) {
      int b = mt * 16 + q * 4 + rg;
      c_state[b * kH + jg] = c[mt][rg];
    }
}
}  // namespace

extern "C" void kernel_launch(void* const* d_in, const int* in_sizes, int n_in,
                              void* d_out, int out_size, void* d_ws,
                              size_t ws_size, hipStream_t stream) {
  const float* x = (const float*)d_in[0];
  const float* wih = (const float*)d_in[1];
  const float* whh = (const float*)d_in[2];
  const float* bih = (const float*)d_in[3];
  const float* bhh = (const float*)d_in[4];
  float* out = (float*)d_out;

  // workspace layout (floats): wf16 | hg | c_state | bias | flags | xg_chunk
  float* wsf = (float*)d_ws;
  _Float16* wf16 = (_Float16*)wsf;                 // 1M halves (2 MB)
  float* hg_f = wsf + 524288;                      // 65536 halves x2 parities
  float* c_state = wsf + 524288 + 32768;
  float* bias = wsf + 524288 + 32768 + 32768;
  float* flagsf = wsf + 524288 + 32768 + 32768 + 2048;  // 128 words
  unsigned* flags = (unsigned*)flagsf;
  float* xgbuf = flagsf + 128;
  _Float16* hg = (_Float16*)hg_f;
  size_t fixed_bytes = (size_t)(xgbuf - wsf) * sizeof(float);

  // largest time-chunk whose xg buffer fits the workspace (constant per call)
  int Tc = 8;
  for (int cand : {1024, 512, 256, 128, 64, 32, 16, 8}) {
    if (fixed_bytes + (size_t)kB * cand * kG * sizeof(float) <= ws_size) {
      Tc = cand;
      break;
    }
  }
  int nChunks = kT / Tc;

  for (int l = 0; l < kL; ++l) {
    prep_bias_kernel<<<(kG + 255) / 256, 256, 0, stream>>>(
        bih + (size_t)l * kG, bhh + (size_t)l * kG, bias);
    prep_wf16_kernel<<<(kG * kH) / 256, 256, 0, stream>>>(
        whh + (size_t)l * kG * kH, wf16);
    // zero hg (both parities) + c_state = 65536 floats
    zero_f32_kernel<<<65536 / 256, 256, 0, stream>>>(hg_f, 65536);
    const float* A = (l == 0) ? x : out;  // layers 2,3 run in place on d_out
    for (int ci = 0; ci < nChunks; ++ci) {
      int t0 = ci * Tc;
      dim3 g(kG / BN, (kB * Tc) / BM);
      proj_kernel<<<g, 256, 0, stream>>>(A, wih + (size_t)l * kG * kH, bias,
                                         xgbuf, t0, Tc);
      zero_f32_kernel<<<1, 128, 0, stream>>>(flagsf, 128);
      recur_mfma<<<RB, 256, 0, stream>>>(wf16, xgbuf, hg, out, c_state, flags,
                                         t0, Tc);
    }
  }
}

// Round 4
// 10355.424 us; speedup vs baseline: 3.8625x; 3.8625x over previous
//
#include <hip/hip_runtime.h>
#include <math.h>

namespace {
constexpr int kB = 64;
constexpr int kT = 1024;
constexpr int kH = 512;
constexpr int kL = 3;
constexpr int kG = 2048;      // 4*H, gate order i,f,g,o
constexpr int GPB = 16;       // blocks per layer group (32 j each)
constexpr int NB = kL * GPB;  // 48 persistent blocks
constexpr int HSLOT = kB * kH;  // 32768 halves per h ping-pong slot

typedef _Float16 half8 __attribute__((ext_vector_type(8)));
typedef float floatx4 __attribute__((ext_vector_type(4)));

// ---------------- device-coherent access helpers (proven r0/r1) ----------
__device__ __forceinline__ half8 ld_h8_dev(const _Float16* p) {
  half8 r;
  asm volatile("global_load_dwordx4 %0, %1, off sc0 sc1" : "=v"(r) : "v"(p));
  return r;
}
__device__ __forceinline__ void st_h_dev(_Float16* p, unsigned v) {
  asm volatile("global_store_short %0, %1, off sc0 sc1" : : "v"(p), "v"(v));
}

// ---------------- prep kernels ----------------
__global__ void zero_f32_kernel(float* __restrict__ p, int n) {
  int i = blockIdx.x * 256 + threadIdx.x;
  if (i < n) p[i] = 0.f;
}

__global__ void prep_bias_kernel(const float* __restrict__ bih,
                                 const float* __restrict__ bhh,
                                 float* __restrict__ bias) {
  int i = blockIdx.x * 256 + threadIdx.x;
  if (i < kL * kG) bias[i] = bih[i] + bhh[i];
}

// wf layout: [l][p][4H][H] halves, p=0: Whh, p=1: Wih (plain row-major f16)
__global__ void prep_w_kernel(const float* __restrict__ whh,
                              const float* __restrict__ wih,
                              _Float16* __restrict__ wf) {
  int i = blockIdx.x * 256 + threadIdx.x;  // 6 * 1048576 total
  int lp = i >> 20;
  int e = i & 1048575;
  const float* s = (lp & 1) ? wih : whh;
  wf[i] = (_Float16)s[(size_t)(lp >> 1) * (kG * kH) + e];
}

// x -> frag-linear f16 per timestep: xf[t][addr(b,k)], addr as h-exchange
// layout: ((b>>4)*16 + (k>>5))*512 + ((k>>3)&3)*128 + (b&15)*8 + (k&7)
__global__ void prep_xf_kernel(const float* __restrict__ x,
                               _Float16* __restrict__ xf) {
  int i = blockIdx.x * 256 + threadIdx.x;  // kB*kT*64
  int k8 = i & 63;   // k-group of 8
  int r = i >> 6;    // b*kT + t
  int t = r & (kT - 1);
  int b = r >> 10;
  const float* s = x + ((size_t)r << 9) + (k8 << 3);
  float4 v0 = *reinterpret_cast<const float4*>(s);
  float4 v1 = *reinterpret_cast<const float4*>(s + 4);
  half8 hv;
  hv[0] = (_Float16)v0.x; hv[1] = (_Float16)v0.y;
  hv[2] = (_Float16)v0.z; hv[3] = (_Float16)v0.w;
  hv[4] = (_Float16)v1.x; hv[5] = (_Float16)v1.y;
  hv[6] = (_Float16)v1.z; hv[7] = (_Float16)v1.w;
  *reinterpret_cast<half8*>(xf + (size_t)t * HSLOT + (b >> 4) * 8192 +
                            (k8 >> 2) * 512 + (k8 & 3) * 128 + (b & 15) * 8) =
      hv;
}

__device__ __forceinline__ float sigf(float x) {
  return 1.f / (1.f + __expf(-x));
}
__device__ __forceinline__ float tanh_fast(float x) {
  float e = __expf(2.f * x);
  return (e - 1.f) / (e + 1.f);
}

// ---------------- wavefront-pipelined persistent recurrence ----------------
// 48 blocks = 3 layer-groups x 16 blocks. Block (l, gb) owns j-slice
// [gb*32, gb*32+32). Waves: pair p = w>>1 (0: Whh*h^l_{t-1}, 1: Wih*input),
// jh = w&1 selects the 16-j half. Layer l at global step s computes local
// t = s - l; one flag barrier over all 48 blocks per s. h and x flow as f16
// frag-linear tiles through the device coherence point (sc0/sc1).
__global__ __launch_bounds__(256, 1) void recur_pipe(
    const _Float16* __restrict__ wf,   // [3][2][2048][512]
    const _Float16* __restrict__ xf,   // [1024][32768] frag-linear x
    const float* __restrict__ bias,    // [3][2048]
    _Float16* __restrict__ hg,         // [3][2][32768] ping-pong
    float* __restrict__ out,           // [64][1024][512]
    unsigned* __restrict__ flags) {    // 48 lines of 16 u32, zeroed
  const int tid = threadIdx.x;
  const int wv = tid >> 6;
  const int lane = tid & 63;
  const int l15 = lane & 15;
  const int q = lane >> 4;
  const int p = wv >> 1;   // matrix select
  const int jh = wv & 1;   // j half
  const int bid = blockIdx.x;
  const int l = bid >> 4;  // layer
  const int gb = bid & 15;
  const int jw = gb * 32 + jh * 16 + l15;  // output hidden column 0..511

  __shared__ __align__(16) _Float16 Ash[2][HSLOT];  // 2 x 64KB staging
  // combine buffer aliases Ash[0] (dead between MFMA-done and next staging)
  float* Csh = reinterpret_cast<float*>(&Ash[0][0]);  // 8192 f32 = 32KB

  // --- persistent weight fragments: matrix p of layer l, j-width 16 ---
  half8 wfrag[4][16];
  {
    const _Float16* wsel = wf + (size_t)(l * 2 + p) * (kG * kH);
#pragma unroll
    for (int g = 0; g < 4; ++g) {
      const _Float16* wr = wsel + (size_t)(g * kH + jw) * kH;
#pragma unroll
      for (int ks = 0; ks < 16; ++ks)
        wfrag[g][ks] = *reinterpret_cast<const half8*>(wr + ks * 32 + q * 8);
    }
  }
  float bb[4];
#pragma unroll
  for (int g = 0; g < 4; ++g) bb[g] = bias[l * kG + g * kH + jw];

  float c[4][4];
#pragma unroll
  for (int mt = 0; mt < 4; ++mt)
#pragma unroll
    for (int rg = 0; rg < 4; ++rg) c[mt][rg] = 0.f;

  const int ksj = jw >> 5;
  const int quadj = (jw >> 3) & 3;
  const int jj = jw & 7;
  const int pl = jh * 64 + lane;  // pair-lane 0..127

  constexpr int S = kT + kL - 1;  // 1026 global steps
  for (int s = 0; s < S; ++s) {
    const int t = s - l;
    const bool active = (t >= 0) && (t < kT);
    float hreg[4][4];

    if (active) {
      // A-source: p0 = own h^l_{t-1}; p1 = x_t (l=0) or h^{l-1}_t
      const _Float16* src =
          (p == 0) ? hg + l * (2 * HSLOT) + ((t & 1) ^ 1) * HSLOT
                   : (l == 0 ? xf + (size_t)t * HSLOT
                             : hg + (l - 1) * (2 * HSLOT) + (t & 1) * HSLOT);
      // stage 64KB/pair into Ash[p]: 2 chunks of 16 x (16B load -> ds_write)
#pragma unroll
      for (int ch = 0; ch < 2; ++ch) {
        half8 stg[16];
#pragma unroll
        for (int it = 0; it < 16; ++it)
          stg[it] = ld_h8_dev(src + (ch * 16 + it) * 1024 + pl * 8);
        asm volatile("s_waitcnt vmcnt(0)" ::: "memory");
        __builtin_amdgcn_sched_barrier(0);
#pragma unroll
        for (int it = 0; it < 16; ++it)
          *reinterpret_cast<half8*>(&Ash[p][(ch * 16 + it) * 1024 + pl * 8]) =
              stg[it];
      }
    }
    __syncthreads();  // s1: staging complete

    floatx4 zero4 = {0.f, 0.f, 0.f, 0.f};
    floatx4 acc[4][4];
#pragma unroll
    for (int mt = 0; mt < 4; ++mt)
#pragma unroll
      for (int g = 0; g < 4; ++g) acc[mt][g] = zero4;

    if (active) {
#pragma unroll
      for (int ks = 0; ks < 16; ++ks) {
        half8 af[4];
#pragma unroll
        for (int mt = 0; mt < 4; ++mt)
          af[mt] = *reinterpret_cast<const half8*>(
              &Ash[p][((mt * 16 + ks) * 64 + lane) * 8]);
#pragma unroll
        for (int mt = 0; mt < 4; ++mt)
#pragma unroll
          for (int g = 0; g < 4; ++g)
            acc[mt][g] = __builtin_amdgcn_mfma_f32_16x16x32_f16(
                af[mt], wfrag[g][ks], acc[mt][g], 0, 0, 0);
      }
    }
    __syncthreads();  // s2: all MFMA done, Ash dead -> Csh usable

    if (active && p == 1) {
#pragma unroll
      for (int mt = 0; mt < 4; ++mt)
#pragma unroll
        for (int g = 0; g < 4; ++g)
          *reinterpret_cast<floatx4*>(
              &Csh[(((jh * 4 + mt) * 4 + g) * 64 + lane) * 4]) = acc[mt][g];
    }
    __syncthreads();  // s3: partials visible

    if (active && p == 0) {
#pragma unroll
      for (int mt = 0; mt < 4; ++mt)
#pragma unroll
        for (int g = 0; g < 4; ++g)
          acc[mt][g] += *reinterpret_cast<const floatx4*>(
              &Csh[(((jh * 4 + mt) * 4 + g) * 64 + lane) * 4]);

      _Float16* hout = hg + l * (2 * HSLOT) + (t & 1) * HSLOT;
#pragma unroll
      for (int mt = 0; mt < 4; ++mt)
#pragma unroll
        for (int rg = 0; rg < 4; ++rg) {
          int b = mt * 16 + q * 4 + rg;
          float gi = acc[mt][0][rg] + bb[0];
          float gf = acc[mt][1][rg] + bb[1];
          float gg = acc[mt][2][rg] + bb[2];
          float go = acc[mt][3][rg] + bb[3];
          float ig = sigf(gi), fg = sigf(gf), zg = tanh_fast(gg),
                og = sigf(go);
          float cn = fg * c[mt][rg] + ig * zg;
          c[mt][rg] = cn;
          float h = og * tanh_fast(cn);
          hreg[mt][rg] = h;
          _Float16 hf = (_Float16)h;
          st_h_dev(hout + (((b >> 4) * 16 + ksj) * 64 + quadj * 16 +
                           (b & 15)) * 8 + jj,
                   (unsigned)__builtin_bit_cast(unsigned short, hf));
        }
    }

    // drain per-wave sc1 stores, then 48-block flag barrier
    asm volatile("s_waitcnt vmcnt(0)" ::: "memory");
    __syncthreads();  // s4: all h stores at coherence point
    if (tid == 0)
      __hip_atomic_fetch_add(flags + bid * 16, 1u, __ATOMIC_RELAXED,
                             __HIP_MEMORY_SCOPE_AGENT);
    if (active && p == 0 && l == kL - 1) {
      // final-layer output (f32, plain) overlaps the poll wait
#pragma unroll
      for (int mt = 0; mt < 4; ++mt)
#pragma unroll
        for (int rg = 0; rg < 4; ++rg) {
          int b = mt * 16 + q * 4 + rg;
          out[(size_t)b * (kT * kH) + (size_t)t * kH + jw] = hreg[mt][rg];
        }
    }
    unsigned tgt = (unsigned)(s + 1);
    if (tid < NB) {
      while (__hip_atomic_load(flags + tid * 16, __ATOMIC_RELAXED,
                               __HIP_MEMORY_SCOPE_AGENT) < tgt)
        __builtin_amdgcn_s_sleep(1);
    }
    __syncthreads();  // s5: step complete everywhere
  }
}
}  // namespace

extern "C" void kernel_launch(void* const* d_in, const int* in_sizes, int n_in,
                              void* d_out, int out_size, void* d_ws,
                              size_t ws_size, hipStream_t stream) {
  const float* x = (const float*)d_in[0];
  const float* wih = (const float*)d_in[1];
  const float* whh = (const float*)d_in[2];
  const float* bih = (const float*)d_in[3];
  const float* bhh = (const float*)d_in[4];
  float* out = (float*)d_out;

  // workspace layout (float units):
  // wf16 (6*1048576 h = 3145728 f) | xf (1024*32768 h = 16777216 f) |
  // hg (196608 h = 98304 f) | bias (6144 f) | flags (768 u32)
  float* wsf = (float*)d_ws;
  _Float16* wf16 = (_Float16*)wsf;
  _Float16* xf = (_Float16*)(wsf + 3145728);
  float* hg_f = wsf + 3145728 + 16777216;
  _Float16* hg = (_Float16*)hg_f;
  float* bias = hg_f + 98304;
  float* flagsf = bias + 6144;
  unsigned* flags = (unsigned*)flagsf;

  // zero hg + bias + flags (contiguous 105216 floats); bias overwritten next
  zero_f32_kernel<<<(105216 + 255) / 256, 256, 0, stream>>>(hg_f, 105216);
  prep_bias_kernel<<<(kL * kG + 255) / 256, 256, 0, stream>>>(bih, bhh, bias);
  prep_w_kernel<<<(6 * 1048576) / 256, 256, 0, stream>>>(whh, wih, wf16);
  prep_xf_kernel<<<(kB * kT * 64) / 256, 256, 0, stream>>>(x, xf);
  recur_pipe<<<NB, 256, 0, stream>>>(wf16, xf, bias, hg, out, flags);
}